// Round 9
// baseline (244.395 us; speedup 1.0000x reference)
//
#include <hip/hip_runtime.h>
#include <hip/hip_bf16.h>

// GCN layer: out = relu( (D^-1/2 A D^-1/2) @ (x @ W) ) over channel dim.
// B=16, C=64, S=2048, Fin=Fout=64.
#define B_ 16
#define C_ 64
#define S_ 2048
#define F_ 64
#define SF (S_ * F_)   // 131072, stride between channels
#define NSI 4          // s-tiles (of 8) per block

typedef __attribute__((ext_vector_type(8))) short short8;   // 8 bf16 (4 VGPRs) MFMA A/B frag
typedef __attribute__((ext_vector_type(4))) float float4_;  // MFMA C/D frag

// bf16-tile XOR-swizzle (halfword units, 16B granules)
#define SWZ(row, col) ((col) ^ (((row) & 7) << 3))
// fp32-tile XOR-swizzle (dword units, 16B granules)
#define SWZ4(row, col) ((col) ^ (((row) & 7) << 2))

__device__ __forceinline__ unsigned short f2bf(float f) {
    // RNE fp32->bf16 via integer ops (proven numerics)
    unsigned int u = __builtin_bit_cast(unsigned int, f);
    u += 0x7fffu + ((u >> 16) & 1u);
    return (unsigned short)(u >> 16);
}

// ---------------------------------------------------------------------------
// Prep (proven): norm_adj -> bf16 [c][d];  wT[o][f] = bf16(weight[f][o])
// ---------------------------------------------------------------------------
__global__ void gcn_prep(const float* __restrict__ adj, const float* __restrict__ wgt,
                         unsigned short* __restrict__ nadj, unsigned short* __restrict__ wT)
{
    __shared__ float dis[C_];
    const int t = threadIdx.x;          // 256 threads
    {
        const int r = t >> 2, q = t & 3;
        float p = 0.f;
        const float* ar = adj + r * C_ + q * 16;
#pragma unroll
        for (int j = 0; j < 16; ++j) p += ar[j];
        p += __shfl_xor(p, 1);
        p += __shfl_xor(p, 2);
        if (q == 0) dis[r] = rsqrtf(p);
    }
    __syncthreads();
    for (int i = t; i < C_ * C_; i += 256) {
        const int c = i >> 6, d = i & 63;
        nadj[i] = f2bf(adj[i] * dis[c] * dis[d]);
        wT[d * F_ + c] = f2bf(wgt[i]);   // wgt[f=c][o=d] -> wT[o][f]
    }
}

// ---------------------------------------------------------------------------
// Main: one block = (b, 32 consecutive s); one wave = one s per iteration,
// NSI=4 iterations of the proven round-7 one-shot body. After the table fill
// there are NO block barriers: each wave stages through its private 4KB LDS
// tile and issues fire-and-forget nontemporal full-line stores.
// ---------------------------------------------------------------------------
__global__ __launch_bounds__(512, 4) void gcn_main(
    const float* __restrict__ x,
    const unsigned short* __restrict__ nadj,
    const unsigned short* __restrict__ wT,
    float* __restrict__ out)
{
    __shared__ __align__(16) unsigned short lds_nadj[C_ * C_];   // 8 KB, swizzled
    __shared__ __align__(16) unsigned short lds_wT[F_ * F_];     // 8 KB, swizzled
    __shared__ __align__(16) float obuf_all[8][16 * 64];         // 4 KB per wave (unions supT)

    const int tid  = threadIdx.x;
    const int w    = tid >> 6;          // wave id 0..7
    const int l    = tid & 63;
    const int lrow = l & 15;
    const int lgrp = l >> 4;            // 0..3

    // ---- cooperative fill of nadj/wT into swizzled LDS (16B per thread each)
    {
        const int fc = tid >> 3;          // row 0..63
        const int fd = (tid & 7) * 8;     // col base
        *(short8*)(lds_nadj + fc * 64 + SWZ(fc, fd)) = *(const short8*)(nadj + fc * 64 + fd);
        *(short8*)(lds_wT  + fc * 64 + SWZ(fc, fd)) = *(const short8*)(wT  + fc * 64 + fd);
    }
    __syncthreads();    // the only block barrier

    const int b     = blockIdx.x >> 6;    // 64 chunks per b
    const int chunk = blockIdx.x & 63;    // chunk of 32 consecutive s

    float* myO = obuf_all[w];                       // fp32 [16][64] view (stage 2)
    unsigned short* myT = (unsigned short*)myO;     // bf16 [16][64] view (stage 1)

#pragma unroll 1
    for (int it = 0; it < NSI; ++it) {
        const int s = chunk * 32 + it * 8 + w;

        // ---- load x A-fragments for all 64 channels (nontemporal; fp32 -> bf16)
        const float* xb = x + (size_t)b * C_ * SF + (size_t)s * F_;
        short8 af[4][2];
#pragma unroll
        for (int dt = 0; dt < 4; ++dt) {
            const float* xr = xb + (size_t)(dt * 16 + lrow) * SF;
#pragma unroll
            for (int ks = 0; ks < 2; ++ks) {
                float4_ u0 = __builtin_nontemporal_load((const float4_*)(xr + ks * 32 + lgrp * 8));
                float4_ u1 = __builtin_nontemporal_load((const float4_*)(xr + ks * 32 + lgrp * 8 + 4));
                short8 a;
#pragma unroll
                for (int j = 0; j < 4; ++j) {
                    a[j]     = (short)f2bf(u0[j]);
                    a[4 + j] = (short)f2bf(u1[j]);
                }
                af[dt][ks] = a;
            }
        }

        // ---- Stage 1: per o-tile, sup[d][o] -> wave-local transpose -> aA regs
        short8 aA[4][2];
#pragma unroll
        for (int ot = 0; ot < 4; ++ot) {
            const int orow = ot * 16 + lrow;
            short8 wf0 = *(const short8*)(lds_wT + orow * 64 + SWZ(lrow, lgrp * 8));
            short8 wf1 = *(const short8*)(lds_wT + orow * 64 + SWZ(lrow, 32 + lgrp * 8));
#pragma unroll
            for (int dt = 0; dt < 4; ++dt) {
                float4_ s1 = {0.f, 0.f, 0.f, 0.f};
                s1 = __builtin_amdgcn_mfma_f32_16x16x32_bf16(af[dt][0], wf0, s1, 0, 0, 0);
                s1 = __builtin_amdgcn_mfma_f32_16x16x32_bf16(af[dt][1], wf1, s1, 0, 0, 0);
                const int dbase = dt * 16 + lgrp * 4;     // C-frag rows = d
                uint2 pk;                                  // lane's col = o = orow
                pk.x = (unsigned)f2bf(s1[0]) | ((unsigned)f2bf(s1[1]) << 16);
                pk.y = (unsigned)f2bf(s1[2]) | ((unsigned)f2bf(s1[3]) << 16);
                *(uint2*)(myT + lrow * 64 + SWZ(lrow, dbase)) = pk;
            }
            // sup^T fragments (A-operand, stage 2): row = o_local = lrow, k = d
            aA[ot][0] = *(const short8*)(myT + lrow * 64 + SWZ(lrow, lgrp * 8));
            aA[ot][1] = *(const short8*)(myT + lrow * 64 + SWZ(lrow, 32 + lgrp * 8));
        }
        // (myT dead once aA loaded; within-wave lgkmcnt ordering protects reuse)

        // ---- Stage 2: per c-tile: MFMA -> relu -> private LDS tile -> NT stores
#pragma unroll 1
        for (int ct = 0; ct < 4; ++ct) {
            const int crow = ct * 16 + lrow;
            short8 an0 = *(const short8*)(lds_nadj + crow * 64 + SWZ(lrow, lgrp * 8));
            short8 an1 = *(const short8*)(lds_nadj + crow * 64 + SWZ(lrow, 32 + lgrp * 8));

#pragma unroll
            for (int ot = 0; ot < 4; ++ot) {
                float4_ acc = {0.f, 0.f, 0.f, 0.f};
                acc = __builtin_amdgcn_mfma_f32_16x16x32_bf16(aA[ot][0], an0, acc, 0, 0, 0);
                acc = __builtin_amdgcn_mfma_f32_16x16x32_bf16(aA[ot][1], an1, acc, 0, 0, 0);
                float4_ r;
#pragma unroll
                for (int j = 0; j < 4; ++j) r[j] = fmaxf(acc[j], 0.f);
                // lane holds out[c=crow][o = ot*16 + lgrp*4 + j]; stage in own tile
                *(float4_*)(myO + lrow * 64 + SWZ4(lrow, ot * 16 + lgrp * 4)) = r;
            }

            // read back + store: 4 instrs, each = 4 c-rows x 256B contiguous runs
#pragma unroll
            for (int t = 0; t < 4; ++t) {
                const int cl  = t * 4 + (l >> 4);       // c-local 0..15
                const int col = (l & 15) * 4;           // dword col 0..60
                float4_ v = *(const float4_*)(myO + cl * 64 + SWZ4(cl, col));
                float* g = out + ((size_t)(b * C_ + ct * 16 + cl) * S_ + s) * F_ + col;
                __builtin_nontemporal_store(v, (float4_*)g);
            }
        }
    }
}

// ---------------------------------------------------------------------------
extern "C" void kernel_launch(void* const* d_in, const int* in_sizes, int n_in,
                              void* d_out, int out_size, void* d_ws, size_t ws_size,
                              hipStream_t stream) {
    const float* x   = (const float*)d_in[0];
    const float* adj = (const float*)d_in[1];
    const float* wgt = (const float*)d_in[2];
    float* out = (float*)d_out;

    unsigned short* nadj = (unsigned short*)d_ws;      // 4096 bf16
    unsigned short* wT   = nadj + C_ * C_;             // 4096 bf16

    gcn_prep<<<1, 256, 0, stream>>>(adj, wgt, nadj, wT);

    dim3 grid(B_ * (S_ / 32));   // 1024 blocks: (b, chunk of 32 s)
    gcn_main<<<grid, 512, 0, stream>>>(x, nadj, wT, out);
}

// Round 10
// 235.740 us; speedup vs baseline: 1.0367x; 1.0367x over previous
//
#include <hip/hip_runtime.h>
#include <hip/hip_bf16.h>

// GCN layer: out = relu( (D^-1/2 A D^-1/2) @ (x @ W) ) over channel dim.
// B=16, C=64, S=2048, Fin=Fout=64.
#define B_ 16
#define C_ 64
#define S_ 2048
#define F_ 64
#define SF (S_ * F_)   // 131072, stride between channels

typedef __attribute__((ext_vector_type(8))) short short8;   // 8 bf16 (4 VGPRs) MFMA A/B frag
typedef __attribute__((ext_vector_type(4))) float float4_;  // MFMA C/D frag

// bf16-tile XOR-swizzle (halfword units, 16B granules)
#define SWZ(row, col) ((col) ^ (((row) & 7) << 3))

__device__ __forceinline__ unsigned short f2bf(float f) {
    // RNE fp32->bf16 via integer ops (proven numerics)
    unsigned int u = __builtin_bit_cast(unsigned int, f);
    u += 0x7fffu + ((u >> 16) & 1u);
    return (unsigned short)(u >> 16);
}

// ---------------------------------------------------------------------------
// Prep (round-7 proven): norm_adj -> bf16 [c][d];  wT[o][f] = bf16(weight[f][o])
// ---------------------------------------------------------------------------
__global__ void gcn_prep(const float* __restrict__ adj, const float* __restrict__ wgt,
                         unsigned short* __restrict__ nadj, unsigned short* __restrict__ wT)
{
    __shared__ float dis[C_];
    const int t = threadIdx.x;
    if (t < C_) {
        float s = 0.f;
        for (int d = 0; d < C_; ++d) s += adj[t * C_ + d];
        dis[t] = rsqrtf(s);
    }
    __syncthreads();
    for (int i = t; i < C_ * C_; i += 256) {
        const int c = i >> 6, d = i & 63;
        nadj[i] = f2bf(adj[i] * dis[c] * dis[d]);
        wT[d * F_ + c] = f2bf(wgt[i]);   // wgt[f=c][o=d] -> wT[o][f]
    }
}

// ---------------------------------------------------------------------------
// Main: one block = (b, 8 consecutive s); one wave = one s (round-7 skeleton).
// Stage 1: sup[d][o] = x[b,d,s,:] @ W ; wave-local transpose (in own obuf
//          region) -> aA regs.                                   [barrier 2]
// Stage 2: out[c][o] via mfma(aA, nadj); relu; pack bf16 into block-wide
//          obuf[c][s][o] (swizzled).                             [barrier 3]
// Store:   wave w owns c-rows 8w..8w+8; per row 2 instrs, each a fully
//          contiguous 1KB NT burst (128B lines complete per instruction).
// Barriers 2/3 are cheap: no global ops outstanding at either point.
// ---------------------------------------------------------------------------
__global__ __launch_bounds__(512, 4) void gcn_main(
    const float* __restrict__ x,
    const unsigned short* __restrict__ nadj,
    const unsigned short* __restrict__ wT,
    float* __restrict__ out)
{
    __shared__ __align__(16) unsigned short lds_nadj[C_ * C_];   // 8 KB, swizzled
    __shared__ __align__(16) unsigned short lds_wT[F_ * F_];     // 8 KB, swizzled
    // 64 KB: stage2 obuf bf16 [c=64][s=8][o'=64]; stage1 supT unions (wave w
    // region = hw [w*1024, w*1024+1024) = rows c = 2w, 2w+1)
    __shared__ __align__(16) unsigned short obuf[C_ * 8 * 64];

    const int tid  = threadIdx.x;
    const int w    = tid >> 6;          // wave id 0..7  == s within tile
    const int l    = tid & 63;
    const int lrow = l & 15;
    const int lgrp = l >> 4;            // 0..3

    // ---- cooperative fill of nadj/wT into swizzled LDS (16B per thread each)
    {
        const int fc = tid >> 3;          // row 0..63
        const int fd = (tid & 7) * 8;     // col base
        *(short8*)(lds_nadj + fc * 64 + SWZ(fc, fd)) = *(const short8*)(nadj + fc * 64 + fd);
        *(short8*)(lds_wT  + fc * 64 + SWZ(fc, fd)) = *(const short8*)(wT  + fc * 64 + fd);
    }
    __syncthreads();    // barrier 1

    const int b  = blockIdx.x >> 8;     // 256 s-tiles per b
    const int st = blockIdx.x & 255;
    const int s  = st * 8 + w;

    // ---- load x A-fragments for all 64 channels (nontemporal; fp32 -> bf16)
    const float* xb = x + (size_t)b * C_ * SF + (size_t)s * F_;
    short8 af[4][2];
#pragma unroll
    for (int dt = 0; dt < 4; ++dt) {
        const float* xr = xb + (size_t)(dt * 16 + lrow) * SF;
#pragma unroll
        for (int ks = 0; ks < 2; ++ks) {
            float4_ u0 = __builtin_nontemporal_load((const float4_*)(xr + ks * 32 + lgrp * 8));
            float4_ u1 = __builtin_nontemporal_load((const float4_*)(xr + ks * 32 + lgrp * 8 + 4));
            short8 a;
#pragma unroll
            for (int j = 0; j < 4; ++j) {
                a[j]     = (short)f2bf(u0[j]);
                a[4 + j] = (short)f2bf(u1[j]);
            }
            af[dt][ks] = a;
        }
    }

    unsigned short* myT = obuf + w * 1024;   // wave-private 2KB stage-1 scratch

    // ---- Stage 1: per o-tile, sup[d][o] -> wave-local transpose -> aA regs
    short8 aA[4][2];
#pragma unroll
    for (int ot = 0; ot < 4; ++ot) {
        const int orow = ot * 16 + lrow;
        short8 wf0 = *(const short8*)(lds_wT + orow * 64 + SWZ(lrow, lgrp * 8));
        short8 wf1 = *(const short8*)(lds_wT + orow * 64 + SWZ(lrow, 32 + lgrp * 8));
#pragma unroll
        for (int dt = 0; dt < 4; ++dt) {
            float4_ s1 = {0.f, 0.f, 0.f, 0.f};
            s1 = __builtin_amdgcn_mfma_f32_16x16x32_bf16(af[dt][0], wf0, s1, 0, 0, 0);
            s1 = __builtin_amdgcn_mfma_f32_16x16x32_bf16(af[dt][1], wf1, s1, 0, 0, 0);
            const int dbase = dt * 16 + lgrp * 4;     // C-frag rows = d
            uint2 pk;                                  // lane's col = o = orow
            pk.x = (unsigned)f2bf(s1[0]) | ((unsigned)f2bf(s1[1]) << 16);
            pk.y = (unsigned)f2bf(s1[2]) | ((unsigned)f2bf(s1[3]) << 16);
            *(uint2*)(myT + lrow * 64 + SWZ(lrow, dbase)) = pk;
        }
        // sup^T fragments (A-operand, stage 2): row = o_local = lrow, k = d
        aA[ot][0] = *(const short8*)(myT + lrow * 64 + SWZ(lrow, lgrp * 8));
        aA[ot][1] = *(const short8*)(myT + lrow * 64 + SWZ(lrow, 32 + lgrp * 8));
    }
    __syncthreads();    // barrier 2: all supT regions dead -> obuf reusable

    // ---- Stage 2: mfma(aA, nadj) -> relu -> bf16 -> obuf[c][s][o'] swizzled
#pragma unroll 1
    for (int ct = 0; ct < 4; ++ct) {
        const int crow = ct * 16 + lrow;
        short8 an0 = *(const short8*)(lds_nadj + crow * 64 + SWZ(lrow, lgrp * 8));
        short8 an1 = *(const short8*)(lds_nadj + crow * 64 + SWZ(lrow, 32 + lgrp * 8));
#pragma unroll
        for (int ot = 0; ot < 4; ++ot) {
            float4_ acc = {0.f, 0.f, 0.f, 0.f};
            acc = __builtin_amdgcn_mfma_f32_16x16x32_bf16(aA[ot][0], an0, acc, 0, 0, 0);
            acc = __builtin_amdgcn_mfma_f32_16x16x32_bf16(aA[ot][1], an1, acc, 0, 0, 0);
            // lane holds out[c=crow][o = ot*16 + lgrp*4 + j] for s = w
            const int o = ot * 16 + lgrp * 4;
            uint2 pk;
            pk.x = (unsigned)f2bf(fmaxf(acc[0], 0.f)) | ((unsigned)f2bf(fmaxf(acc[1], 0.f)) << 16);
            pk.y = (unsigned)f2bf(fmaxf(acc[2], 0.f)) | ((unsigned)f2bf(fmaxf(acc[3], 0.f)) << 16);
            *(uint2*)(obuf + crow * 512 + w * 64 + (o ^ ((crow & 7) << 3))) = pk;
        }
    }
    __syncthreads();    // barrier 3: obuf complete (LDS-only drain; no vmem pending)

    // ---- Store phase: wave w -> c-rows 8w..8w+8; per row two 1KB contiguous
    // NT bursts (lane l covers dwords [l*4, l*4+4) of the 1KB half-run).
#pragma unroll
    for (int cr = 0; cr < 8; ++cr) {
        const int c = w * 8 + cr;
        float* grow = out + ((size_t)(b * C_ + c) * S_ + st * 8) * F_;
#pragma unroll
        for (int ph = 0; ph < 2; ++ph) {
            // source: s = ph*4 + (l>>4), o = (l&15)*4  (4 bf16 = 8B)
            const int sl = ph * 4 + (l >> 4);
            const int o  = (l & 15) * 4;
            uint2 v = *(const uint2*)(obuf + c * 512 + sl * 64 + (o ^ ((c & 7) << 3)));
            float4_ r;
            r[0] = __builtin_bit_cast(float, v.x << 16);
            r[1] = __builtin_bit_cast(float, v.x & 0xFFFF0000u);
            r[2] = __builtin_bit_cast(float, v.y << 16);
            r[3] = __builtin_bit_cast(float, v.y & 0xFFFF0000u);
            __builtin_nontemporal_store(r, (float4_*)(grow + ph * 256 + l * 4));
        }
    }
}

// ---------------------------------------------------------------------------
extern "C" void kernel_launch(void* const* d_in, const int* in_sizes, int n_in,
                              void* d_out, int out_size, void* d_ws, size_t ws_size,
                              hipStream_t stream) {
    const float* x   = (const float*)d_in[0];
    const float* adj = (const float*)d_in[1];
    const float* wgt = (const float*)d_in[2];
    float* out = (float*)d_out;

    unsigned short* nadj = (unsigned short*)d_ws;      // 4096 bf16
    unsigned short* wT   = nadj + C_ * C_;             // 4096 bf16

    gcn_prep<<<1, 256, 0, stream>>>(adj, wgt, nadj, wT);

    dim3 grid(B_ * (S_ / 8));   // 4096 blocks: (b, s-tile of 8)
    gcn_main<<<grid, 512, 0, stream>>>(x, nadj, wT, out);
}